// Round 7
// baseline (503.172 us; speedup 1.0000x reference)
//
#include <hip/hip_runtime.h>

__device__ __forceinline__ float leaky(float v) { return v >= 0.f ? v : 0.01f * v; }

__device__ __forceinline__ void fma4(float4& a, float s, const float4& w) {
    a.x = fmaf(s, w.x, a.x); a.y = fmaf(s, w.y, a.y);
    a.z = fmaf(s, w.z, a.z); a.w = fmaf(s, w.w, a.w);
}

__device__ __forceinline__ unsigned short f2bf(float x) {  // RNE
    unsigned b = __float_as_uint(x);
    return (unsigned short)((b + 0x7FFFu + ((b >> 16) & 1u)) >> 16);
}
__device__ __forceinline__ float bf2f(unsigned short u) {
    return __uint_as_float(((unsigned)u) << 16);
}

typedef __attribute__((ext_vector_type(8))) short short8v;
typedef __attribute__((ext_vector_type(4))) float float4v;

// ---------------------------------------------------------------------------
// CSR build (unchanged)
__global__ void k_deg(const int* __restrict__ col, int E, int* __restrict__ deg) {
    int e = blockIdx.x * blockDim.x + threadIdx.x;
    if (e < E) atomicAdd(&deg[col[e]], 1);
}

__global__ __launch_bounds__(256) void k_scan_part(const int* __restrict__ deg,
                                                   int* __restrict__ part,
                                                   int* __restrict__ bsum, int N) {
    __shared__ int tmp[256];
    int tid = threadIdx.x;
    int i = blockIdx.x * 256 + tid;
    int v = (i < N) ? deg[i] : 0;
    tmp[tid] = v;
    __syncthreads();
    for (int ofs = 1; ofs < 256; ofs <<= 1) {
        int t = (tid >= ofs) ? tmp[tid - ofs] : 0;
        __syncthreads();
        tmp[tid] += t;
        __syncthreads();
    }
    int incl = tmp[tid];
    if (i < N) part[i] = incl - v;
    if (tid == 255) bsum[blockIdx.x] = incl;
}

__global__ __launch_bounds__(256) void k_scan_sums(const int* __restrict__ bsum,
                                                   int* __restrict__ boff, int NB,
                                                   int* __restrict__ offs_last) {
    __shared__ int tmp[256];
    int tid = threadIdx.x;
    int v = (tid < NB) ? bsum[tid] : 0;
    tmp[tid] = v;
    __syncthreads();
    for (int ofs = 1; ofs < 256; ofs <<= 1) {
        int t = (tid >= ofs) ? tmp[tid - ofs] : 0;
        __syncthreads();
        tmp[tid] += t;
        __syncthreads();
    }
    int incl = tmp[tid];
    if (tid < NB) boff[tid] = incl - v;
    if (tid == 255) offs_last[0] = incl;
}

__global__ __launch_bounds__(256) void k_scan_final(const int* __restrict__ part,
                                                    const int* __restrict__ boff,
                                                    const int* __restrict__ deg,
                                                    int* __restrict__ offs,
                                                    int* __restrict__ pos,
                                                    float* __restrict__ dinv, int N) {
    int i = blockIdx.x * 256 + threadIdx.x;
    if (i < N) {
        int o = part[i] + boff[blockIdx.x];
        offs[i] = o;
        pos[i] = o;
        dinv[i] = rsqrtf((float)(deg[i] + 1));
    }
}

__global__ void k_fill(const int* __restrict__ row, const int* __restrict__ col, int E,
                       int* __restrict__ pos, int* __restrict__ csr) {
    int e = blockIdx.x * blockDim.x + threadIdx.x;
    if (e < E) {
        int p = atomicAdd(&pos[col[e]], 1);
        csr[p] = row[e];
    }
}

// ---------------------------------------------------------------------------
// Phase A — MFMA rewrite. Per block: 64 nodes (4 waves x 16), one feature.
// W packed once into LDS in B-fragment order as bf16 hi/lo split; X streamed
// global->reg as fp32, split to bf16 hi/lo; 3 MFMAs/chunk give ~fp32 accuracy.
// No barriers in the K-loop. Tail blocks run the fused tiny linears.
__global__ __launch_bounds__(256) void k_featB(
    const float* __restrict__ s, const float* __restrict__ d, const float* __restrict__ t,
    const float* __restrict__ Ws, const float* __restrict__ bs2,
    const float* __restrict__ Wd, const float* __restrict__ bd2,
    const float* __restrict__ Wt, const float* __restrict__ bt2,
    const float* __restrict__ prof, const float* __restrict__ pers,
    const float* __restrict__ Wp, const float* __restrict__ bp,
    const float* __restrict__ Wpe, const float* __restrict__ bpe,
    float* __restrict__ x1g, int N, int NG) {
    __shared__ short8v wfv[3072];  // [hi:1536][lo:1536] fragments, 48 KB

    const int bid = blockIdx.x;
    const int tid = threadIdx.x;

    if (bid >= 3 * NG) {  // ---- fused tiny linears ----
        int n = (bid - 3 * NG) * 256 + tid;
        if (n >= N) return;
        float pv[5], pe[7];
#pragma unroll
        for (int i = 0; i < 5; ++i) pv[i] = prof[(size_t)n * 5 + i];
#pragma unroll
        for (int i = 0; i < 7; ++i) pe[i] = pers[(size_t)n * 7 + i];
        float o[16];
#pragma unroll
        for (int j = 0; j < 8; ++j) {
            float a = bp[j];
#pragma unroll
            for (int i = 0; i < 5; ++i) a = fmaf(pv[i], Wp[i * 8 + j], a);
            o[j] = leaky(a);
            float a2 = bpe[j];
#pragma unroll
            for (int i = 0; i < 7; ++i) a2 = fmaf(pe[i], Wpe[i * 8 + j], a2);
            o[8 + j] = leaky(a2);
        }
#pragma unroll
        for (int v = 0; v < 4; ++v)
            *reinterpret_cast<float4*>(x1g + (size_t)n * 64 + 48 + v * 4) =
                make_float4(o[v * 4], o[v * 4 + 1], o[v * 4 + 2], o[v * 4 + 3]);
        return;
    }

    const int f = bid / NG;
    const int grp = bid - f * NG;
    const float* __restrict__ X = (f == 0) ? s : ((f == 1) ? d : t);
    const float* __restrict__ W = (f == 0) ? Ws : ((f == 1) ? Wd : Wt);
    const float* __restrict__ B = (f == 0) ? bs2 : ((f == 1) ? bd2 : bt2);
    const int n0 = grp * 64;
    const int lane = tid & 63;
    const int wid = tid >> 6;

    // ---- pack W into fragment order (coalesced float4 reads, scalar LDS writes)
    // frag element: lane l of chunk c holds W[c*32 + 8*(l>>4) + i][l&15], i=0..7
    short* wfs = (short*)wfv;
#pragma unroll
    for (int v = 0; v < 12; ++v) {
        int idx4 = tid + v * 256;          // 3072 float4 = 768x16
        float4 w4 = *reinterpret_cast<const float4*>(W + (size_t)idx4 * 4);
        int k = idx4 >> 2;                 // W row
        int j0 = (idx4 & 3) * 4;           // W col base
        int c = k >> 5, g = (k >> 3) & 3, i = k & 7;
        float wq[4] = {w4.x, w4.y, w4.z, w4.w};
#pragma unroll
        for (int q = 0; q < 4; ++q) {
            int sl = (c * 64 + g * 16 + j0 + q) * 8 + i;
            unsigned short h = f2bf(wq[q]);
            wfs[sl] = (short)h;
            wfs[12288 + sl] = (short)f2bf(wq[q] - bf2f(h));
        }
    }
    __syncthreads();

    // ---- main loop: wave = 16 nodes, full K, no barriers
    const int nb = n0 + wid * 16;
    int mrow = nb + (lane & 15); if (mrow >= N) mrow = N - 1;
    const float* base = X + (size_t)mrow * 768 + ((lane >> 4) << 3);

    float4 xa = *reinterpret_cast<const float4*>(base);
    float4 xb = *reinterpret_cast<const float4*>(base + 4);
    float4v acc = {0.f, 0.f, 0.f, 0.f};

    for (int c = 0; c < 24; ++c) {
        int cn = (c < 23) ? c + 1 : 23;
        float4 ya = *reinterpret_cast<const float4*>(base + cn * 32);
        float4 yb = *reinterpret_cast<const float4*>(base + cn * 32 + 4);
        float xs[8] = {xa.x, xa.y, xa.z, xa.w, xb.x, xb.y, xb.z, xb.w};
        short8v xh, xl;
#pragma unroll
        for (int i = 0; i < 8; ++i) {
            unsigned short h = f2bf(xs[i]);
            xh[i] = (short)h;
            xl[i] = (short)f2bf(xs[i] - bf2f(h));
        }
        short8v wh = wfv[c * 64 + lane];
        short8v wl = wfv[1536 + c * 64 + lane];
        acc = __builtin_amdgcn_mfma_f32_16x16x32_bf16(xh, wh, acc, 0, 0, 0);
        acc = __builtin_amdgcn_mfma_f32_16x16x32_bf16(xl, wh, acc, 0, 0, 0);
        acc = __builtin_amdgcn_mfma_f32_16x16x32_bf16(xh, wl, acc, 0, 0, 0);
        xa = ya; xb = yb;
    }

    // epilogue: D lane layout col=lane&15, row=(lane>>4)*4+r
    int j = lane & 15;
    float bb = B[j];
#pragma unroll
    for (int r = 0; r < 4; ++r) {
        int n = nb + ((lane >> 4) << 2) + r;
        if (n < N) x1g[(size_t)n * 64 + f * 16 + j] = leaky(acc[r] + bb);
    }
}

// ---------------------------------------------------------------------------
// Generic 64x64 node-matmul (unchanged)
__global__ __launch_bounds__(256, 4) void k_mm64(const float* __restrict__ xin,
                                                 const float* __restrict__ W,
                                                 const float* __restrict__ bias,
                                                 const float* __restrict__ dinvv,
                                                 int act, int tobf16,
                                                 void* __restrict__ outp, int N) {
    __shared__ float4 xt4[1024];  // [64][16] swizzled
    __shared__ float4 wt4[1024];  // [64 k][16 j4] linear
    const int tid = threadIdx.x;
    const int n0 = blockIdx.x * 64;
#pragma unroll
    for (int v = 0; v < 4; ++v) {
        int L = v * 256 + tid;
        int n = L >> 4, c4 = L & 15;
        int nn = n0 + n; if (nn >= N) nn = N - 1;
        xt4[n * 16 + (c4 ^ (n & 15))] = *reinterpret_cast<const float4*>(xin + (size_t)nn * 64 + c4 * 4);
        wt4[L] = *reinterpret_cast<const float4*>(W + (size_t)L * 4);
    }
    __syncthreads();
    const int nq = tid & 15;
    const int jq = tid >> 4;  // 0..15
    float4 acc[4];
#pragma unroll
    for (int g = 0; g < 4; ++g) acc[g] = make_float4(0.f, 0.f, 0.f, 0.f);
    for (int k = 0; k < 64; k += 4) {
        float4 w0 = wt4[(k + 0) * 16 + jq];
        float4 w1 = wt4[(k + 1) * 16 + jq];
        float4 w2 = wt4[(k + 2) * 16 + jq];
        float4 w3 = wt4[(k + 3) * 16 + jq];
        int k4 = k >> 2;
#pragma unroll
        for (int g = 0; g < 4; ++g) {
            int n = nq + (g << 4);
            float4 xv = xt4[n * 16 + (k4 ^ (n & 15))];
            fma4(acc[g], xv.x, w0);
            fma4(acc[g], xv.y, w1);
            fma4(acc[g], xv.z, w2);
            fma4(acc[g], xv.w, w3);
        }
    }
    float4 bb = make_float4(0.f, 0.f, 0.f, 0.f);
    if (bias) bb = *reinterpret_cast<const float4*>(bias + jq * 4);
#pragma unroll
    for (int g = 0; g < 4; ++g) {
        int n = nq + (g << 4);
        if (n0 + n >= N) continue;
        float4 r = acc[g];
        r.x += bb.x; r.y += bb.y; r.z += bb.z; r.w += bb.w;
        if (act) { r.x = leaky(r.x); r.y = leaky(r.y); r.z = leaky(r.z); r.w = leaky(r.w); }
        if (dinvv) {
            float dv = dinvv[n0 + n];
            r.x *= dv; r.y *= dv; r.z *= dv; r.w *= dv;
        }
        if (tobf16) {
            ushort4 o;
            o.x = f2bf(r.x); o.y = f2bf(r.y); o.z = f2bf(r.z); o.w = f2bf(r.w);
            *reinterpret_cast<ushort4*>((unsigned short*)outp + (size_t)(n0 + n) * 64 + jq * 4) = o;
        } else {
            *reinterpret_cast<float4*>((float*)outp + (size_t)(n0 + n) * 64 + jq * 4) = r;
        }
    }
}

// ---------------------------------------------------------------------------
// Gather aggregation (unchanged): bf16 z, scalar CSR loads, 8-deep unroll.
__global__ __launch_bounds__(256) void k_agg(const unsigned short* __restrict__ z,
                                             const int* __restrict__ offs,
                                             const int* __restrict__ csr,
                                             const float* __restrict__ dinv,
                                             const float* __restrict__ bias,
                                             const float* __restrict__ x1,
                                             float* __restrict__ xout, int N) {
    int lane = threadIdx.x & 63;
    int c = blockIdx.x * 4 + (threadIdx.x >> 6);
    if (c >= N) return;
    int s = __builtin_amdgcn_readfirstlane(offs[c]);
    int e = __builtin_amdgcn_readfirstlane(offs[c + 1]);
    const unsigned short* zl = z + lane;
    float acc = bf2f(zl[(size_t)c * 64]);  // self-loop term
    float a0 = 0.f, a1 = 0.f, a2 = 0.f, a3 = 0.f;
    float a4 = 0.f, a5 = 0.f, a6 = 0.f, a7 = 0.f;
    int j = s;
    for (; j + 8 <= e; j += 8) {
        int r0 = csr[j + 0], r1 = csr[j + 1], r2 = csr[j + 2], r3 = csr[j + 3];
        int r4 = csr[j + 4], r5 = csr[j + 5], r6 = csr[j + 6], r7 = csr[j + 7];
        a0 += bf2f(zl[(size_t)r0 * 64]);
        a1 += bf2f(zl[(size_t)r1 * 64]);
        a2 += bf2f(zl[(size_t)r2 * 64]);
        a3 += bf2f(zl[(size_t)r3 * 64]);
        a4 += bf2f(zl[(size_t)r4 * 64]);
        a5 += bf2f(zl[(size_t)r5 * 64]);
        a6 += bf2f(zl[(size_t)r6 * 64]);
        a7 += bf2f(zl[(size_t)r7 * 64]);
    }
    for (; j < e; ++j) acc += bf2f(zl[(size_t)csr[j] * 64]);
    acc += ((a0 + a1) + (a2 + a3)) + ((a4 + a5) + (a6 + a7));
    xout[(size_t)c * 64 + lane] = dinv[c] * acc + bias[lane] + x1[(size_t)c * 64 + lane];
}

// ---------------------------------------------------------------------------
// head (unchanged)
__global__ __launch_bounds__(256) void k_head(const float* __restrict__ xin,
                                              const float* __restrict__ Wo1,
                                              const float* __restrict__ bo1,
                                              const float* __restrict__ Wo2,
                                              const float* __restrict__ bo2,
                                              float* __restrict__ out, int N) {
    __shared__ float xsg[64][65];
    __shared__ float wg[64][65];
    __shared__ float hs[64][65];
    __shared__ float wo2[128];
    const int tid = threadIdx.x;
    const int n0 = blockIdx.x * 64;
#pragma unroll
    for (int v = 0; v < 4; ++v) {
        int idx = tid + v * 256;
        int n = idx >> 4;
        int jj = (idx & 15) << 2;
        float4 xv = make_float4(0.f, 0.f, 0.f, 0.f);
        if (n0 + n < N) xv = *reinterpret_cast<const float4*>(xin + (size_t)(n0 + n) * 64 + jj);
        xsg[n][jj] = xv.x; xsg[n][jj + 1] = xv.y; xsg[n][jj + 2] = xv.z; xsg[n][jj + 3] = xv.w;
        float4 w = *reinterpret_cast<const float4*>(Wo1 + (size_t)n * 64 + jj);
        wg[n][jj] = w.x; wg[n][jj + 1] = w.y; wg[n][jj + 2] = w.z; wg[n][jj + 3] = w.w;
    }
    if (tid < 128) wo2[tid] = Wo2[tid];
    __syncthreads();
    int j = tid & 63;
    int g = tid >> 6;
    float bj = bo1[j];
    for (int i = 0; i < 16; ++i) {
        int n = g * 16 + i;
        float a = bj;
#pragma unroll
        for (int k = 0; k < 64; ++k) a += xsg[n][k] * wg[k][j];
        hs[n][j] = leaky(a);
    }
    __syncthreads();
    if (tid < 128) {
        int n = tid >> 1;
        int j2 = tid & 1;
        float a = bo2[j2];
#pragma unroll
        for (int k = 0; k < 64; ++k) a += hs[n][k] * wo2[k * 2 + j2];
        if (n0 + n < N) out[(size_t)(n0 + n) * 2 + j2] = 1.f / (1.f + expf(-a));
    }
}

// ---------------------------------------------------------------------------
extern "C" void kernel_launch(void* const* d_in, const int* in_sizes, int n_in,
                              void* d_out, int out_size, void* d_ws, size_t ws_size,
                              hipStream_t stream) {
    const float* screen   = (const float*)d_in[0];
    const float* des      = (const float*)d_in[1];
    const float* tweet    = (const float*)d_in[2];
    const float* profile  = (const float*)d_in[3];
    const float* personal = (const float*)d_in[4];
    const int*   edge     = (const int*)d_in[5];
    const float* Ws  = (const float*)d_in[6],  *bs  = (const float*)d_in[7];
    const float* Wd  = (const float*)d_in[8],  *bd  = (const float*)d_in[9];
    const float* Wt  = (const float*)d_in[10], *bt  = (const float*)d_in[11];
    const float* Wp  = (const float*)d_in[12], *bp  = (const float*)d_in[13];
    const float* Wpe = (const float*)d_in[14], *bpe = (const float*)d_in[15];
    const float* Wl  = (const float*)d_in[16], *bl  = (const float*)d_in[17];
    const float* Wg1 = (const float*)d_in[18], *bg1 = (const float*)d_in[19];
    const float* Wg2 = (const float*)d_in[20], *bg2 = (const float*)d_in[21];
    const float* Wg3 = (const float*)d_in[22], *bg3 = (const float*)d_in[23];
    const float* Wo1 = (const float*)d_in[24], *bo1 = (const float*)d_in[25];
    const float* Wo2 = (const float*)d_in[26], *bo2 = (const float*)d_in[27];

    const int N = in_sizes[0] / 768;   // 50000
    const int E = in_sizes[5] / 2;     // 1600000
    const int* row = edge;
    const int* col = edge + E;

    size_t off = 0;
    auto alloc = [&](size_t bytes) -> void* {
        void* p = (char*)d_ws + off;
        off += (bytes + 255) & ~(size_t)255;
        return p;
    };
    const size_t NF = (size_t)N * 64;
    float* x1   = (float*)alloc(NF * 4);
    float* xa   = (float*)alloc(NF * 4);
    float* xb   = (float*)alloc(NF * 4);
    unsigned short* z = (unsigned short*)alloc(NF * 2);
    float* dinv = (float*)alloc((size_t)N * 4);
    int* deg  = (int*)alloc((size_t)N * 4);
    int* part = (int*)alloc((size_t)N * 4);
    int* offs = (int*)alloc((size_t)(N + 1) * 4);
    int* pos  = (int*)alloc((size_t)N * 4);
    int* csr  = (int*)alloc((size_t)E * 4);
    const int NB = (N + 255) / 256;
    int* bsum = (int*)alloc((size_t)NB * 4);
    int* boff = (int*)alloc((size_t)NB * 4);
    (void)ws_size; (void)n_in; (void)out_size;

    // CSR build
    hipMemsetAsync(deg, 0, (size_t)N * 4, stream);
    k_deg<<<(E + 255) / 256, 256, 0, stream>>>(col, E, deg);
    k_scan_part<<<NB, 256, 0, stream>>>(deg, part, bsum, N);
    k_scan_sums<<<1, 256, 0, stream>>>(bsum, boff, NB, offs + N);
    k_scan_final<<<NB, 256, 0, stream>>>(part, boff, deg, offs, pos, dinv, N);
    k_fill<<<(E + 255) / 256, 256, 0, stream>>>(row, col, E, pos, csr);

    // Phase A: MFMA feature linears (64-node tiles) + fused tiny linears
    const int NG = (N + 63) / 64;
    const int NSM = (N + 255) / 256;
    k_featB<<<NG * 3 + NSM, 256, 0, stream>>>(screen, des, tweet,
                                              Ws, bs, Wd, bd, Wt, bt,
                                              profile, personal, Wp, bp, Wpe, bpe,
                                              x1, N, NG);

    const int NGB = (N + 63) / 64;
    // x = leaky(x1 @ Wl + bl)
    k_mm64<<<NGB, 256, 0, stream>>>(x1, Wl, bl, nullptr, 1, 0, xa, N);

    const int NAB = (N + 3) / 4;
    // layer 1
    k_mm64<<<NGB, 256, 0, stream>>>(xa, Wg1, nullptr, dinv, 0, 1, z, N);
    k_agg<<<NAB, 256, 0, stream>>>(z, offs, csr, dinv, bg1, x1, xb, N);
    // layer 2
    k_mm64<<<NGB, 256, 0, stream>>>(xb, Wg2, nullptr, dinv, 0, 1, z, N);
    k_agg<<<NAB, 256, 0, stream>>>(z, offs, csr, dinv, bg2, x1, xa, N);
    // layer 3
    k_mm64<<<NGB, 256, 0, stream>>>(xa, Wg3, nullptr, dinv, 0, 1, z, N);
    k_agg<<<NAB, 256, 0, stream>>>(z, offs, csr, dinv, bg3, x1, xb, N);

    // head
    k_head<<<NGB, 256, 0, stream>>>(xb, Wo1, bo1, Wo2, bo2, (float*)d_out, N);
}

// Round 8
// 489.606 us; speedup vs baseline: 1.0277x; 1.0277x over previous
//
#include <hip/hip_runtime.h>

__device__ __forceinline__ float leaky(float v) { return v >= 0.f ? v : 0.01f * v; }

__device__ __forceinline__ void fma4(float4& a, float s, const float4& w) {
    a.x = fmaf(s, w.x, a.x); a.y = fmaf(s, w.y, a.y);
    a.z = fmaf(s, w.z, a.z); a.w = fmaf(s, w.w, a.w);
}

__device__ __forceinline__ unsigned short f2bf(float x) {  // RNE
    unsigned b = __float_as_uint(x);
    return (unsigned short)((b + 0x7FFFu + ((b >> 16) & 1u)) >> 16);
}
__device__ __forceinline__ float bf2f(unsigned short u) {
    return __uint_as_float(((unsigned)u) << 16);
}

typedef __attribute__((ext_vector_type(8))) short short8v;
typedef __attribute__((ext_vector_type(4))) float float4v;

// ---------------------------------------------------------------------------
// CSR build (unchanged)
__global__ void k_deg(const int* __restrict__ col, int E, int* __restrict__ deg) {
    int e = blockIdx.x * blockDim.x + threadIdx.x;
    if (e < E) atomicAdd(&deg[col[e]], 1);
}

__global__ __launch_bounds__(256) void k_scan_part(const int* __restrict__ deg,
                                                   int* __restrict__ part,
                                                   int* __restrict__ bsum, int N) {
    __shared__ int tmp[256];
    int tid = threadIdx.x;
    int i = blockIdx.x * 256 + tid;
    int v = (i < N) ? deg[i] : 0;
    tmp[tid] = v;
    __syncthreads();
    for (int ofs = 1; ofs < 256; ofs <<= 1) {
        int t = (tid >= ofs) ? tmp[tid - ofs] : 0;
        __syncthreads();
        tmp[tid] += t;
        __syncthreads();
    }
    int incl = tmp[tid];
    if (i < N) part[i] = incl - v;
    if (tid == 255) bsum[blockIdx.x] = incl;
}

__global__ __launch_bounds__(256) void k_scan_sums(const int* __restrict__ bsum,
                                                   int* __restrict__ boff, int NB,
                                                   int* __restrict__ offs_last) {
    __shared__ int tmp[256];
    int tid = threadIdx.x;
    int v = (tid < NB) ? bsum[tid] : 0;
    tmp[tid] = v;
    __syncthreads();
    for (int ofs = 1; ofs < 256; ofs <<= 1) {
        int t = (tid >= ofs) ? tmp[tid - ofs] : 0;
        __syncthreads();
        tmp[tid] += t;
        __syncthreads();
    }
    int incl = tmp[tid];
    if (tid < NB) boff[tid] = incl - v;
    if (tid == 255) offs_last[0] = incl;
}

__global__ __launch_bounds__(256) void k_scan_final(const int* __restrict__ part,
                                                    const int* __restrict__ boff,
                                                    const int* __restrict__ deg,
                                                    int* __restrict__ offs,
                                                    int* __restrict__ pos,
                                                    float* __restrict__ dinv, int N) {
    int i = blockIdx.x * 256 + threadIdx.x;
    if (i < N) {
        int o = part[i] + boff[blockIdx.x];
        offs[i] = o;
        pos[i] = o;
        dinv[i] = rsqrtf((float)(deg[i] + 1));
    }
}

__global__ void k_fill(const int* __restrict__ row, const int* __restrict__ col, int E,
                       int* __restrict__ pos, int* __restrict__ csr) {
    int e = blockIdx.x * blockDim.x + threadIdx.x;
    if (e < E) {
        int p = atomicAdd(&pos[col[e]], 1);
        csr[p] = row[e];
    }
}

// ---------------------------------------------------------------------------
// Phase A — MFMA + 4-deep register prefetch ring. 512 threads = 8 waves =
// 128 nodes per block; fully-unrolled K loop (static ring indices); 8 loads
// per wave in flight; no barriers in the K loop.
__global__ __launch_bounds__(512) void k_featB(
    const float* __restrict__ s, const float* __restrict__ d, const float* __restrict__ t,
    const float* __restrict__ Ws, const float* __restrict__ bs2,
    const float* __restrict__ Wd, const float* __restrict__ bd2,
    const float* __restrict__ Wt, const float* __restrict__ bt2,
    const float* __restrict__ prof, const float* __restrict__ pers,
    const float* __restrict__ Wp, const float* __restrict__ bp,
    const float* __restrict__ Wpe, const float* __restrict__ bpe,
    float* __restrict__ x1g, int N, int NG) {
    __shared__ short8v wfv[3072];  // [hi:1536][lo:1536] fragments, 48 KB

    const int bid = blockIdx.x;
    const int tid = threadIdx.x;

    if (bid >= 3 * NG) {  // ---- fused tiny linears ----
        int n = (bid - 3 * NG) * 512 + tid;
        if (n >= N) return;
        float pv[5], pe[7];
#pragma unroll
        for (int i = 0; i < 5; ++i) pv[i] = prof[(size_t)n * 5 + i];
#pragma unroll
        for (int i = 0; i < 7; ++i) pe[i] = pers[(size_t)n * 7 + i];
        float o[16];
#pragma unroll
        for (int j = 0; j < 8; ++j) {
            float a = bp[j];
#pragma unroll
            for (int i = 0; i < 5; ++i) a = fmaf(pv[i], Wp[i * 8 + j], a);
            o[j] = leaky(a);
            float a2 = bpe[j];
#pragma unroll
            for (int i = 0; i < 7; ++i) a2 = fmaf(pe[i], Wpe[i * 8 + j], a2);
            o[8 + j] = leaky(a2);
        }
#pragma unroll
        for (int v = 0; v < 4; ++v)
            *reinterpret_cast<float4*>(x1g + (size_t)n * 64 + 48 + v * 4) =
                make_float4(o[v * 4], o[v * 4 + 1], o[v * 4 + 2], o[v * 4 + 3]);
        return;
    }

    const int f = bid / NG;
    const int grp = bid - f * NG;
    const float* __restrict__ X = (f == 0) ? s : ((f == 1) ? d : t);
    const float* __restrict__ W = (f == 0) ? Ws : ((f == 1) ? Wd : Wt);
    const float* __restrict__ B = (f == 0) ? bs2 : ((f == 1) ? bd2 : bt2);
    const int n0 = grp * 128;
    const int lane = tid & 63;
    const int wid = tid >> 6;  // 0..7

    // ---- pack W into fragment order (hi/lo bf16 split)
    short* wfs = (short*)wfv;
#pragma unroll
    for (int v = 0; v < 6; ++v) {
        int idx4 = tid + v * 512;          // 3072 float4 = 768x16
        float4 w4 = *reinterpret_cast<const float4*>(W + (size_t)idx4 * 4);
        int k = idx4 >> 2;                 // W row
        int j0 = (idx4 & 3) * 4;           // W col base
        int c = k >> 5, g = (k >> 3) & 3, i = k & 7;
        float wq[4] = {w4.x, w4.y, w4.z, w4.w};
#pragma unroll
        for (int q = 0; q < 4; ++q) {
            int sl = (c * 64 + g * 16 + j0 + q) * 8 + i;
            unsigned short h = f2bf(wq[q]);
            wfs[sl] = (short)h;
            wfs[12288 + sl] = (short)f2bf(wq[q] - bf2f(h));
        }
    }
    __syncthreads();

    // ---- main loop: wave = 16 nodes, 4-deep prefetch ring, no barriers
    const int nb = n0 + wid * 16;
    int mrow = nb + (lane & 15); if (mrow >= N) mrow = N - 1;
    const float* base = X + (size_t)mrow * 768 + ((lane >> 4) << 3);

    float4 pa[4], pb[4];
#pragma unroll
    for (int u = 0; u < 4; ++u) {
        pa[u] = *reinterpret_cast<const float4*>(base + u * 32);
        pb[u] = *reinterpret_cast<const float4*>(base + u * 32 + 4);
    }
    float4v acc = {0.f, 0.f, 0.f, 0.f};

#pragma unroll
    for (int c = 0; c < 24; ++c) {
        const int u = c & 3;
        float xs[8] = {pa[u].x, pa[u].y, pa[u].z, pa[u].w,
                       pb[u].x, pb[u].y, pb[u].z, pb[u].w};
        if (c + 4 < 24) {  // refill ring slot (resolved at compile time)
            pa[u] = *reinterpret_cast<const float4*>(base + (c + 4) * 32);
            pb[u] = *reinterpret_cast<const float4*>(base + (c + 4) * 32 + 4);
        }
        short8v xh, xl;
#pragma unroll
        for (int i = 0; i < 8; ++i) {
            unsigned short h = f2bf(xs[i]);
            xh[i] = (short)h;
            xl[i] = (short)f2bf(xs[i] - bf2f(h));
        }
        short8v wh = wfv[c * 64 + lane];
        short8v wl = wfv[1536 + c * 64 + lane];
        acc = __builtin_amdgcn_mfma_f32_16x16x32_bf16(xh, wh, acc, 0, 0, 0);
        acc = __builtin_amdgcn_mfma_f32_16x16x32_bf16(xl, wh, acc, 0, 0, 0);
        acc = __builtin_amdgcn_mfma_f32_16x16x32_bf16(xh, wl, acc, 0, 0, 0);
    }

    // epilogue: D lane layout col=lane&15, row=(lane>>4)*4+r
    int j = lane & 15;
    float bb = B[j];
#pragma unroll
    for (int r = 0; r < 4; ++r) {
        int n = nb + ((lane >> 4) << 2) + r;
        if (n < N) x1g[(size_t)n * 64 + f * 16 + j] = leaky(acc[r] + bb);
    }
}

// ---------------------------------------------------------------------------
// Generic 64x64 node-matmul (unchanged)
__global__ __launch_bounds__(256, 4) void k_mm64(const float* __restrict__ xin,
                                                 const float* __restrict__ W,
                                                 const float* __restrict__ bias,
                                                 const float* __restrict__ dinvv,
                                                 int act, int tobf16,
                                                 void* __restrict__ outp, int N) {
    __shared__ float4 xt4[1024];  // [64][16] swizzled
    __shared__ float4 wt4[1024];  // [64 k][16 j4] linear
    const int tid = threadIdx.x;
    const int n0 = blockIdx.x * 64;
#pragma unroll
    for (int v = 0; v < 4; ++v) {
        int L = v * 256 + tid;
        int n = L >> 4, c4 = L & 15;
        int nn = n0 + n; if (nn >= N) nn = N - 1;
        xt4[n * 16 + (c4 ^ (n & 15))] = *reinterpret_cast<const float4*>(xin + (size_t)nn * 64 + c4 * 4);
        wt4[L] = *reinterpret_cast<const float4*>(W + (size_t)L * 4);
    }
    __syncthreads();
    const int nq = tid & 15;
    const int jq = tid >> 4;  // 0..15
    float4 acc[4];
#pragma unroll
    for (int g = 0; g < 4; ++g) acc[g] = make_float4(0.f, 0.f, 0.f, 0.f);
    for (int k = 0; k < 64; k += 4) {
        float4 w0 = wt4[(k + 0) * 16 + jq];
        float4 w1 = wt4[(k + 1) * 16 + jq];
        float4 w2 = wt4[(k + 2) * 16 + jq];
        float4 w3 = wt4[(k + 3) * 16 + jq];
        int k4 = k >> 2;
#pragma unroll
        for (int g = 0; g < 4; ++g) {
            int n = nq + (g << 4);
            float4 xv = xt4[n * 16 + (k4 ^ (n & 15))];
            fma4(acc[g], xv.x, w0);
            fma4(acc[g], xv.y, w1);
            fma4(acc[g], xv.z, w2);
            fma4(acc[g], xv.w, w3);
        }
    }
    float4 bb = make_float4(0.f, 0.f, 0.f, 0.f);
    if (bias) bb = *reinterpret_cast<const float4*>(bias + jq * 4);
#pragma unroll
    for (int g = 0; g < 4; ++g) {
        int n = nq + (g << 4);
        if (n0 + n >= N) continue;
        float4 r = acc[g];
        r.x += bb.x; r.y += bb.y; r.z += bb.z; r.w += bb.w;
        if (act) { r.x = leaky(r.x); r.y = leaky(r.y); r.z = leaky(r.z); r.w = leaky(r.w); }
        if (dinvv) {
            float dv = dinvv[n0 + n];
            r.x *= dv; r.y *= dv; r.z *= dv; r.w *= dv;
        }
        if (tobf16) {
            ushort4 o;
            o.x = f2bf(r.x); o.y = f2bf(r.y); o.z = f2bf(r.z); o.w = f2bf(r.w);
            *reinterpret_cast<ushort4*>((unsigned short*)outp + (size_t)(n0 + n) * 64 + jq * 4) = o;
        } else {
            *reinterpret_cast<float4*>((float*)outp + (size_t)(n0 + n) * 64 + jq * 4) = r;
        }
    }
}

// ---------------------------------------------------------------------------
// Gather aggregation (unchanged): bf16 z, scalar CSR loads, 8-deep unroll.
__global__ __launch_bounds__(256) void k_agg(const unsigned short* __restrict__ z,
                                             const int* __restrict__ offs,
                                             const int* __restrict__ csr,
                                             const float* __restrict__ dinv,
                                             const float* __restrict__ bias,
                                             const float* __restrict__ x1,
                                             float* __restrict__ xout, int N) {
    int lane = threadIdx.x & 63;
    int c = blockIdx.x * 4 + (threadIdx.x >> 6);
    if (c >= N) return;
    int s = __builtin_amdgcn_readfirstlane(offs[c]);
    int e = __builtin_amdgcn_readfirstlane(offs[c + 1]);
    const unsigned short* zl = z + lane;
    float acc = bf2f(zl[(size_t)c * 64]);  // self-loop term
    float a0 = 0.f, a1 = 0.f, a2 = 0.f, a3 = 0.f;
    float a4 = 0.f, a5 = 0.f, a6 = 0.f, a7 = 0.f;
    int j = s;
    for (; j + 8 <= e; j += 8) {
        int r0 = csr[j + 0], r1 = csr[j + 1], r2 = csr[j + 2], r3 = csr[j + 3];
        int r4 = csr[j + 4], r5 = csr[j + 5], r6 = csr[j + 6], r7 = csr[j + 7];
        a0 += bf2f(zl[(size_t)r0 * 64]);
        a1 += bf2f(zl[(size_t)r1 * 64]);
        a2 += bf2f(zl[(size_t)r2 * 64]);
        a3 += bf2f(zl[(size_t)r3 * 64]);
        a4 += bf2f(zl[(size_t)r4 * 64]);
        a5 += bf2f(zl[(size_t)r5 * 64]);
        a6 += bf2f(zl[(size_t)r6 * 64]);
        a7 += bf2f(zl[(size_t)r7 * 64]);
    }
    for (; j < e; ++j) acc += bf2f(zl[(size_t)csr[j] * 64]);
    acc += ((a0 + a1) + (a2 + a3)) + ((a4 + a5) + (a6 + a7));
    xout[(size_t)c * 64 + lane] = dinv[c] * acc + bias[lane] + x1[(size_t)c * 64 + lane];
}

// ---------------------------------------------------------------------------
// head (unchanged)
__global__ __launch_bounds__(256) void k_head(const float* __restrict__ xin,
                                              const float* __restrict__ Wo1,
                                              const float* __restrict__ bo1,
                                              const float* __restrict__ Wo2,
                                              const float* __restrict__ bo2,
                                              float* __restrict__ out, int N) {
    __shared__ float xsg[64][65];
    __shared__ float wg[64][65];
    __shared__ float hs[64][65];
    __shared__ float wo2[128];
    const int tid = threadIdx.x;
    const int n0 = blockIdx.x * 64;
#pragma unroll
    for (int v = 0; v < 4; ++v) {
        int idx = tid + v * 256;
        int n = idx >> 4;
        int jj = (idx & 15) << 2;
        float4 xv = make_float4(0.f, 0.f, 0.f, 0.f);
        if (n0 + n < N) xv = *reinterpret_cast<const float4*>(xin + (size_t)(n0 + n) * 64 + jj);
        xsg[n][jj] = xv.x; xsg[n][jj + 1] = xv.y; xsg[n][jj + 2] = xv.z; xsg[n][jj + 3] = xv.w;
        float4 w = *reinterpret_cast<const float4*>(Wo1 + (size_t)n * 64 + jj);
        wg[n][jj] = w.x; wg[n][jj + 1] = w.y; wg[n][jj + 2] = w.z; wg[n][jj + 3] = w.w;
    }
    if (tid < 128) wo2[tid] = Wo2[tid];
    __syncthreads();
    int j = tid & 63;
    int g = tid >> 6;
    float bj = bo1[j];
    for (int i = 0; i < 16; ++i) {
        int n = g * 16 + i;
        float a = bj;
#pragma unroll
        for (int k = 0; k < 64; ++k) a += xsg[n][k] * wg[k][j];
        hs[n][j] = leaky(a);
    }
    __syncthreads();
    if (tid < 128) {
        int n = tid >> 1;
        int j2 = tid & 1;
        float a = bo2[j2];
#pragma unroll
        for (int k = 0; k < 64; ++k) a += hs[n][k] * wo2[k * 2 + j2];
        if (n0 + n < N) out[(size_t)(n0 + n) * 2 + j2] = 1.f / (1.f + expf(-a));
    }
}

// ---------------------------------------------------------------------------
extern "C" void kernel_launch(void* const* d_in, const int* in_sizes, int n_in,
                              void* d_out, int out_size, void* d_ws, size_t ws_size,
                              hipStream_t stream) {
    const float* screen   = (const float*)d_in[0];
    const float* des      = (const float*)d_in[1];
    const float* tweet    = (const float*)d_in[2];
    const float* profile  = (const float*)d_in[3];
    const float* personal = (const float*)d_in[4];
    const int*   edge     = (const int*)d_in[5];
    const float* Ws  = (const float*)d_in[6],  *bs  = (const float*)d_in[7];
    const float* Wd  = (const float*)d_in[8],  *bd  = (const float*)d_in[9];
    const float* Wt  = (const float*)d_in[10], *bt  = (const float*)d_in[11];
    const float* Wp  = (const float*)d_in[12], *bp  = (const float*)d_in[13];
    const float* Wpe = (const float*)d_in[14], *bpe = (const float*)d_in[15];
    const float* Wl  = (const float*)d_in[16], *bl  = (const float*)d_in[17];
    const float* Wg1 = (const float*)d_in[18], *bg1 = (const float*)d_in[19];
    const float* Wg2 = (const float*)d_in[20], *bg2 = (const float*)d_in[21];
    const float* Wg3 = (const float*)d_in[22], *bg3 = (const float*)d_in[23];
    const float* Wo1 = (const float*)d_in[24], *bo1 = (const float*)d_in[25];
    const float* Wo2 = (const float*)d_in[26], *bo2 = (const float*)d_in[27];

    const int N = in_sizes[0] / 768;   // 50000
    const int E = in_sizes[5] / 2;     // 1600000
    const int* row = edge;
    const int* col = edge + E;

    size_t off = 0;
    auto alloc = [&](size_t bytes) -> void* {
        void* p = (char*)d_ws + off;
        off += (bytes + 255) & ~(size_t)255;
        return p;
    };
    const size_t NF = (size_t)N * 64;
    float* x1   = (float*)alloc(NF * 4);
    float* xa   = (float*)alloc(NF * 4);
    float* xb   = (float*)alloc(NF * 4);
    unsigned short* z = (unsigned short*)alloc(NF * 2);
    float* dinv = (float*)alloc((size_t)N * 4);
    int* deg  = (int*)alloc((size_t)N * 4);
    int* part = (int*)alloc((size_t)N * 4);
    int* offs = (int*)alloc((size_t)(N + 1) * 4);
    int* pos  = (int*)alloc((size_t)N * 4);
    int* csr  = (int*)alloc((size_t)E * 4);
    const int NB = (N + 255) / 256;
    int* bsum = (int*)alloc((size_t)NB * 4);
    int* boff = (int*)alloc((size_t)NB * 4);
    (void)ws_size; (void)n_in; (void)out_size;

    // CSR build
    hipMemsetAsync(deg, 0, (size_t)N * 4, stream);
    k_deg<<<(E + 255) / 256, 256, 0, stream>>>(col, E, deg);
    k_scan_part<<<NB, 256, 0, stream>>>(deg, part, bsum, N);
    k_scan_sums<<<1, 256, 0, stream>>>(bsum, boff, NB, offs + N);
    k_scan_final<<<NB, 256, 0, stream>>>(part, boff, deg, offs, pos, dinv, N);
    k_fill<<<(E + 255) / 256, 256, 0, stream>>>(row, col, E, pos, csr);

    // Phase A: MFMA feature linears (128-node tiles, 512 threads) + tiny linears
    const int NG = (N + 127) / 128;
    const int NSM = (N + 511) / 512;
    k_featB<<<NG * 3 + NSM, 512, 0, stream>>>(screen, des, tweet,
                                              Ws, bs, Wd, bd, Wt, bt,
                                              profile, personal, Wp, bp, Wpe, bpe,
                                              x1, N, NG);

    const int NGB = (N + 63) / 64;
    // x = leaky(x1 @ Wl + bl)
    k_mm64<<<NGB, 256, 0, stream>>>(x1, Wl, bl, nullptr, 1, 0, xa, N);

    const int NAB = (N + 3) / 4;
    // layer 1
    k_mm64<<<NGB, 256, 0, stream>>>(xa, Wg1, nullptr, dinv, 0, 1, z, N);
    k_agg<<<NAB, 256, 0, stream>>>(z, offs, csr, dinv, bg1, x1, xb, N);
    // layer 2
    k_mm64<<<NGB, 256, 0, stream>>>(xb, Wg2, nullptr, dinv, 0, 1, z, N);
    k_agg<<<NAB, 256, 0, stream>>>(z, offs, csr, dinv, bg2, x1, xa, N);
    // layer 3
    k_mm64<<<NGB, 256, 0, stream>>>(xa, Wg3, nullptr, dinv, 0, 1, z, N);
    k_agg<<<NAB, 256, 0, stream>>>(z, offs, csr, dinv, bg3, x1, xb, N);

    // head
    k_head<<<NGB, 256, 0, stream>>>(xb, Wo1, bo1, Wo2, bo2, (float*)d_out, N);
}

// Round 9
// 478.921 us; speedup vs baseline: 1.0506x; 1.0223x over previous
//
#include <hip/hip_runtime.h>

__device__ __forceinline__ float leaky(float v) { return v >= 0.f ? v : 0.01f * v; }

__device__ __forceinline__ void fma4(float4& a, float s, const float4& w) {
    a.x = fmaf(s, w.x, a.x); a.y = fmaf(s, w.y, a.y);
    a.z = fmaf(s, w.z, a.z); a.w = fmaf(s, w.w, a.w);
}

__device__ __forceinline__ unsigned short f2bf(float x) {  // RNE
    unsigned b = __float_as_uint(x);
    return (unsigned short)((b + 0x7FFFu + ((b >> 16) & 1u)) >> 16);
}
__device__ __forceinline__ float bf2f(unsigned short u) {
    return __uint_as_float(((unsigned)u) << 16);
}

typedef __attribute__((ext_vector_type(8))) short short8v;
typedef __attribute__((ext_vector_type(4))) float float4v;

// ---------------------------------------------------------------------------
// CSR build (unchanged)
__global__ void k_deg(const int* __restrict__ col, int E, int* __restrict__ deg) {
    int e = blockIdx.x * blockDim.x + threadIdx.x;
    if (e < E) atomicAdd(&deg[col[e]], 1);
}

__global__ __launch_bounds__(256) void k_scan_part(const int* __restrict__ deg,
                                                   int* __restrict__ part,
                                                   int* __restrict__ bsum, int N) {
    __shared__ int tmp[256];
    int tid = threadIdx.x;
    int i = blockIdx.x * 256 + tid;
    int v = (i < N) ? deg[i] : 0;
    tmp[tid] = v;
    __syncthreads();
    for (int ofs = 1; ofs < 256; ofs <<= 1) {
        int t = (tid >= ofs) ? tmp[tid - ofs] : 0;
        __syncthreads();
        tmp[tid] += t;
        __syncthreads();
    }
    int incl = tmp[tid];
    if (i < N) part[i] = incl - v;
    if (tid == 255) bsum[blockIdx.x] = incl;
}

__global__ __launch_bounds__(256) void k_scan_sums(const int* __restrict__ bsum,
                                                   int* __restrict__ boff, int NB,
                                                   int* __restrict__ offs_last) {
    __shared__ int tmp[256];
    int tid = threadIdx.x;
    int v = (tid < NB) ? bsum[tid] : 0;
    tmp[tid] = v;
    __syncthreads();
    for (int ofs = 1; ofs < 256; ofs <<= 1) {
        int t = (tid >= ofs) ? tmp[tid - ofs] : 0;
        __syncthreads();
        tmp[tid] += t;
        __syncthreads();
    }
    int incl = tmp[tid];
    if (tid < NB) boff[tid] = incl - v;
    if (tid == 255) offs_last[0] = incl;
}

__global__ __launch_bounds__(256) void k_scan_final(const int* __restrict__ part,
                                                    const int* __restrict__ boff,
                                                    const int* __restrict__ deg,
                                                    int* __restrict__ offs,
                                                    int* __restrict__ pos,
                                                    float* __restrict__ dinv, int N) {
    int i = blockIdx.x * 256 + threadIdx.x;
    if (i < N) {
        int o = part[i] + boff[blockIdx.x];
        offs[i] = o;
        pos[i] = o;
        dinv[i] = rsqrtf((float)(deg[i] + 1));
    }
}

__global__ void k_fill(const int* __restrict__ row, const int* __restrict__ col, int E,
                       int* __restrict__ pos, int* __restrict__ csr) {
    int e = blockIdx.x * blockDim.x + threadIdx.x;
    if (e < E) {
        int p = atomicAdd(&pos[col[e]], 1);
        csr[p] = row[e];
    }
}

// ---------------------------------------------------------------------------
// Phase A — unchanged from R8 (MFMA, 512 threads, prefetch ring).
__global__ __launch_bounds__(512) void k_featB(
    const float* __restrict__ s, const float* __restrict__ d, const float* __restrict__ t,
    const float* __restrict__ Ws, const float* __restrict__ bs2,
    const float* __restrict__ Wd, const float* __restrict__ bd2,
    const float* __restrict__ Wt, const float* __restrict__ bt2,
    const float* __restrict__ prof, const float* __restrict__ pers,
    const float* __restrict__ Wp, const float* __restrict__ bp,
    const float* __restrict__ Wpe, const float* __restrict__ bpe,
    float* __restrict__ x1g, int N, int NG) {
    __shared__ short8v wfv[3072];  // [hi:1536][lo:1536] fragments, 48 KB

    const int bid = blockIdx.x;
    const int tid = threadIdx.x;

    if (bid >= 3 * NG) {  // ---- fused tiny linears ----
        int n = (bid - 3 * NG) * 512 + tid;
        if (n >= N) return;
        float pv[5], pe[7];
#pragma unroll
        for (int i = 0; i < 5; ++i) pv[i] = prof[(size_t)n * 5 + i];
#pragma unroll
        for (int i = 0; i < 7; ++i) pe[i] = pers[(size_t)n * 7 + i];
        float o[16];
#pragma unroll
        for (int j = 0; j < 8; ++j) {
            float a = bp[j];
#pragma unroll
            for (int i = 0; i < 5; ++i) a = fmaf(pv[i], Wp[i * 8 + j], a);
            o[j] = leaky(a);
            float a2 = bpe[j];
#pragma unroll
            for (int i = 0; i < 7; ++i) a2 = fmaf(pe[i], Wpe[i * 8 + j], a2);
            o[8 + j] = leaky(a2);
        }
#pragma unroll
        for (int v = 0; v < 4; ++v)
            *reinterpret_cast<float4*>(x1g + (size_t)n * 64 + 48 + v * 4) =
                make_float4(o[v * 4], o[v * 4 + 1], o[v * 4 + 2], o[v * 4 + 3]);
        return;
    }

    const int f = bid / NG;
    const int grp = bid - f * NG;
    const float* __restrict__ X = (f == 0) ? s : ((f == 1) ? d : t);
    const float* __restrict__ W = (f == 0) ? Ws : ((f == 1) ? Wd : Wt);
    const float* __restrict__ B = (f == 0) ? bs2 : ((f == 1) ? bd2 : bt2);
    const int n0 = grp * 128;
    const int lane = tid & 63;
    const int wid = tid >> 6;  // 0..7

    short* wfs = (short*)wfv;
#pragma unroll
    for (int v = 0; v < 6; ++v) {
        int idx4 = tid + v * 512;          // 3072 float4 = 768x16
        float4 w4 = *reinterpret_cast<const float4*>(W + (size_t)idx4 * 4);
        int k = idx4 >> 2;
        int j0 = (idx4 & 3) * 4;
        int c = k >> 5, g = (k >> 3) & 3, i = k & 7;
        float wq[4] = {w4.x, w4.y, w4.z, w4.w};
#pragma unroll
        for (int q = 0; q < 4; ++q) {
            int sl = (c * 64 + g * 16 + j0 + q) * 8 + i;
            unsigned short h = f2bf(wq[q]);
            wfs[sl] = (short)h;
            wfs[12288 + sl] = (short)f2bf(wq[q] - bf2f(h));
        }
    }
    __syncthreads();

    const int nb = n0 + wid * 16;
    int mrow = nb + (lane & 15); if (mrow >= N) mrow = N - 1;
    const float* base = X + (size_t)mrow * 768 + ((lane >> 4) << 3);

    float4 pa[4], pb[4];
#pragma unroll
    for (int u = 0; u < 4; ++u) {
        pa[u] = *reinterpret_cast<const float4*>(base + u * 32);
        pb[u] = *reinterpret_cast<const float4*>(base + u * 32 + 4);
    }
    float4v acc = {0.f, 0.f, 0.f, 0.f};

#pragma unroll
    for (int c = 0; c < 24; ++c) {
        const int u = c & 3;
        float xs[8] = {pa[u].x, pa[u].y, pa[u].z, pa[u].w,
                       pb[u].x, pb[u].y, pb[u].z, pb[u].w};
        if (c + 4 < 24) {
            pa[u] = *reinterpret_cast<const float4*>(base + (c + 4) * 32);
            pb[u] = *reinterpret_cast<const float4*>(base + (c + 4) * 32 + 4);
        }
        short8v xh, xl;
#pragma unroll
        for (int i = 0; i < 8; ++i) {
            unsigned short h = f2bf(xs[i]);
            xh[i] = (short)h;
            xl[i] = (short)f2bf(xs[i] - bf2f(h));
        }
        short8v wh = wfv[c * 64 + lane];
        short8v wl = wfv[1536 + c * 64 + lane];
        acc = __builtin_amdgcn_mfma_f32_16x16x32_bf16(xh, wh, acc, 0, 0, 0);
        acc = __builtin_amdgcn_mfma_f32_16x16x32_bf16(xl, wh, acc, 0, 0, 0);
        acc = __builtin_amdgcn_mfma_f32_16x16x32_bf16(xh, wl, acc, 0, 0, 0);
    }

    int j = lane & 15;
    float bb = B[j];
#pragma unroll
    for (int r = 0; r < 4; ++r) {
        int n = nb + ((lane >> 4) << 2) + r;
        if (n < N) x1g[(size_t)n * 64 + f * 16 + j] = leaky(acc[r] + bb);
    }
}

// ---------------------------------------------------------------------------
// Fused lin + gcn1-matmul: h = leaky(x1@Wl+bl) (LDS only), z = (h@Wg1)*dinv.
__global__ __launch_bounds__(256) void k_lin1(const float* __restrict__ x1,
                                              const float* __restrict__ Wl,
                                              const float* __restrict__ bl,
                                              const float* __restrict__ Wg1,
                                              const float* __restrict__ dinvv,
                                              unsigned short* __restrict__ z, int N) {
    __shared__ float4 xt4[1024];  // [64][16] swizzled (x1, then h)
    __shared__ float4 wt4[1024];  // weights
    const int tid = threadIdx.x;
    const int n0 = blockIdx.x * 64;
    const int nq = tid & 15;
    const int jq = tid >> 4;  // 0..15

#pragma unroll
    for (int v = 0; v < 4; ++v) {
        int L = v * 256 + tid;
        int n = L >> 4, c4 = L & 15;
        int nn = n0 + n; if (nn >= N) nn = N - 1;
        xt4[n * 16 + (c4 ^ (n & 15))] = *reinterpret_cast<const float4*>(x1 + (size_t)nn * 64 + c4 * 4);
        wt4[L] = *reinterpret_cast<const float4*>(Wl + (size_t)L * 4);
    }
    __syncthreads();

    float4 acc[4];
#pragma unroll
    for (int g = 0; g < 4; ++g) acc[g] = make_float4(0.f, 0.f, 0.f, 0.f);
    for (int k = 0; k < 64; k += 4) {
        float4 w0 = wt4[(k + 0) * 16 + jq];
        float4 w1 = wt4[(k + 1) * 16 + jq];
        float4 w2 = wt4[(k + 2) * 16 + jq];
        float4 w3 = wt4[(k + 3) * 16 + jq];
        int k4 = k >> 2;
#pragma unroll
        for (int g = 0; g < 4; ++g) {
            int n = nq + (g << 4);
            float4 xv = xt4[n * 16 + (k4 ^ (n & 15))];
            fma4(acc[g], xv.x, w0);
            fma4(acc[g], xv.y, w1);
            fma4(acc[g], xv.z, w2);
            fma4(acc[g], xv.w, w3);
        }
    }
    float4 bb = *reinterpret_cast<const float4*>(bl + jq * 4);
    __syncthreads();  // all reads of xt4/wt4 done

    // h -> xt4 (same swizzle), Wg1 -> wt4
#pragma unroll
    for (int g = 0; g < 4; ++g) {
        int n = nq + (g << 4);
        float4 h;
        h.x = leaky(acc[g].x + bb.x);
        h.y = leaky(acc[g].y + bb.y);
        h.z = leaky(acc[g].z + bb.z);
        h.w = leaky(acc[g].w + bb.w);
        xt4[n * 16 + (jq ^ (n & 15))] = h;
    }
#pragma unroll
    for (int v = 0; v < 4; ++v) {
        int L = v * 256 + tid;
        wt4[L] = *reinterpret_cast<const float4*>(Wg1 + (size_t)L * 4);
    }
    __syncthreads();

#pragma unroll
    for (int g = 0; g < 4; ++g) acc[g] = make_float4(0.f, 0.f, 0.f, 0.f);
    for (int k = 0; k < 64; k += 4) {
        float4 w0 = wt4[(k + 0) * 16 + jq];
        float4 w1 = wt4[(k + 1) * 16 + jq];
        float4 w2 = wt4[(k + 2) * 16 + jq];
        float4 w3 = wt4[(k + 3) * 16 + jq];
        int k4 = k >> 2;
#pragma unroll
        for (int g = 0; g < 4; ++g) {
            int n = nq + (g << 4);
            float4 xv = xt4[n * 16 + (k4 ^ (n & 15))];
            fma4(acc[g], xv.x, w0);
            fma4(acc[g], xv.y, w1);
            fma4(acc[g], xv.z, w2);
            fma4(acc[g], xv.w, w3);
        }
    }
#pragma unroll
    for (int g = 0; g < 4; ++g) {
        int n = nq + (g << 4);
        if (n0 + n >= N) continue;
        float dv = dinvv[n0 + n];
        ushort4 o;
        o.x = f2bf(acc[g].x * dv); o.y = f2bf(acc[g].y * dv);
        o.z = f2bf(acc[g].z * dv); o.w = f2bf(acc[g].w * dv);
        *reinterpret_cast<ushort4*>(z + (size_t)(n0 + n) * 64 + jq * 4) = o;
    }
}

// ---------------------------------------------------------------------------
// Generic 64x64 node-matmul (layers 2,3): z = (xin@W)*dinv, bf16 out.
__global__ __launch_bounds__(256, 4) void k_mm64(const float* __restrict__ xin,
                                                 const float* __restrict__ W,
                                                 const float* __restrict__ dinvv,
                                                 unsigned short* __restrict__ z, int N) {
    __shared__ float4 xt4[1024];  // [64][16] swizzled
    __shared__ float4 wt4[1024];
    const int tid = threadIdx.x;
    const int n0 = blockIdx.x * 64;
#pragma unroll
    for (int v = 0; v < 4; ++v) {
        int L = v * 256 + tid;
        int n = L >> 4, c4 = L & 15;
        int nn = n0 + n; if (nn >= N) nn = N - 1;
        xt4[n * 16 + (c4 ^ (n & 15))] = *reinterpret_cast<const float4*>(xin + (size_t)nn * 64 + c4 * 4);
        wt4[L] = *reinterpret_cast<const float4*>(W + (size_t)L * 4);
    }
    __syncthreads();
    const int nq = tid & 15;
    const int jq = tid >> 4;
    float4 acc[4];
#pragma unroll
    for (int g = 0; g < 4; ++g) acc[g] = make_float4(0.f, 0.f, 0.f, 0.f);
    for (int k = 0; k < 64; k += 4) {
        float4 w0 = wt4[(k + 0) * 16 + jq];
        float4 w1 = wt4[(k + 1) * 16 + jq];
        float4 w2 = wt4[(k + 2) * 16 + jq];
        float4 w3 = wt4[(k + 3) * 16 + jq];
        int k4 = k >> 2;
#pragma unroll
        for (int g = 0; g < 4; ++g) {
            int n = nq + (g << 4);
            float4 xv = xt4[n * 16 + (k4 ^ (n & 15))];
            fma4(acc[g], xv.x, w0);
            fma4(acc[g], xv.y, w1);
            fma4(acc[g], xv.z, w2);
            fma4(acc[g], xv.w, w3);
        }
    }
#pragma unroll
    for (int g = 0; g < 4; ++g) {
        int n = nq + (g << 4);
        if (n0 + n >= N) continue;
        float dv = dinvv[n0 + n];
        ushort4 o;
        o.x = f2bf(acc[g].x * dv); o.y = f2bf(acc[g].y * dv);
        o.z = f2bf(acc[g].z * dv); o.w = f2bf(acc[g].w * dv);
        *reinterpret_cast<ushort4*>(z + (size_t)(n0 + n) * 64 + jq * 4) = o;
    }
}

// ---------------------------------------------------------------------------
// Gather aggregation v2: paired-edge dword gathers. lanes 0-31 = edge j,
// lanes 32-63 = edge j+1; each lane covers 2 bf16 features (one dword).
// Halves combined once at the end via shfl_xor(32). Scalar csr loads +
// cndmask select keep the index path on SGPRs.
__global__ __launch_bounds__(256) void k_agg(const unsigned short* __restrict__ z,
                                             const int* __restrict__ offs,
                                             const int* __restrict__ csr,
                                             const float* __restrict__ dinv,
                                             const float* __restrict__ bias,
                                             const float* __restrict__ x1,
                                             float* __restrict__ xout, int N) {
    int lane = threadIdx.x & 63;
    int c = blockIdx.x * 4 + (threadIdx.x >> 6);
    if (c >= N) return;
    int s = __builtin_amdgcn_readfirstlane(offs[c]);
    int e = __builtin_amdgcn_readfirstlane(offs[c + 1]);
    const int half = lane >> 5;
    const int d = lane & 31;
    const unsigned* __restrict__ zr = (const unsigned*)z;  // 32 dwords / row

    float ax = 0.f, ay = 0.f;
    if (half == 0) {  // self-loop once
        unsigned sv = zr[(size_t)c * 32 + d];
        ax = bf2f((unsigned short)(sv & 0xffffu));
        ay = bf2f((unsigned short)(sv >> 16));
    }
    float ux[8] = {0, 0, 0, 0, 0, 0, 0, 0};
    float uy[8] = {0, 0, 0, 0, 0, 0, 0, 0};
    int j = s;
    for (; j + 16 <= e; j += 16) {
#pragma unroll
        for (int u = 0; u < 8; ++u) {
            int r0 = csr[j + 2 * u];
            int r1 = csr[j + 2 * u + 1];
            int r = half ? r1 : r0;
            unsigned v = zr[(size_t)r * 32 + d];
            ux[u] += bf2f((unsigned short)(v & 0xffffu));
            uy[u] += bf2f((unsigned short)(v >> 16));
        }
    }
    for (; j + 2 <= e; j += 2) {
        int r0 = csr[j];
        int r1 = csr[j + 1];
        int r = half ? r1 : r0;
        unsigned v = zr[(size_t)r * 32 + d];
        ax += bf2f((unsigned short)(v & 0xffffu));
        ay += bf2f((unsigned short)(v >> 16));
    }
    if (j < e && half == 0) {  // odd leftover
        int r = csr[j];
        unsigned v = zr[(size_t)r * 32 + d];
        ax += bf2f((unsigned short)(v & 0xffffu));
        ay += bf2f((unsigned short)(v >> 16));
    }
    float tx = ax + ((ux[0] + ux[1]) + (ux[2] + ux[3])) + ((ux[4] + ux[5]) + (ux[6] + ux[7]));
    float ty = ay + ((uy[0] + uy[1]) + (uy[2] + uy[3])) + ((uy[4] + uy[5]) + (uy[6] + uy[7]));
    tx += __shfl_xor(tx, 32);
    ty += __shfl_xor(ty, 32);
    if (half == 0) {
        float dv = dinv[c];
        float2 bb = reinterpret_cast<const float2*>(bias)[d];
        float2 xx = *reinterpret_cast<const float2*>(x1 + (size_t)c * 64 + 2 * d);
        float2 o;
        o.x = dv * tx + bb.x + xx.x;
        o.y = dv * ty + bb.y + xx.y;
        *reinterpret_cast<float2*>(xout + (size_t)c * 64 + 2 * d) = o;
    }
}

// ---------------------------------------------------------------------------
// head (unchanged)
__global__ __launch_bounds__(256) void k_head(const float* __restrict__ xin,
                                              const float* __restrict__ Wo1,
                                              const float* __restrict__ bo1,
                                              const float* __restrict__ Wo2,
                                              const float* __restrict__ bo2,
                                              float* __restrict__ out, int N) {
    __shared__ float xsg[64][65];
    __shared__ float wg[64][65];
    __shared__ float hs[64][65];
    __shared__ float wo2[128];
    const int tid = threadIdx.x;
    const int n0 = blockIdx.x * 64;
#pragma unroll
    for (int v = 0; v < 4; ++v) {
        int idx = tid + v * 256;
        int n = idx >> 4;
        int jj = (idx & 15) << 2;
        float4 xv = make_float4(0.f, 0.f, 0.f, 0.f);
        if (n0 + n < N) xv = *reinterpret_cast<const float4*>(xin + (size_t)(n0 + n) * 64 + jj);
        xsg[n][jj] = xv.x; xsg[n][jj + 1] = xv.y; xsg[n][jj + 2] = xv.z; xsg[n][jj + 3] = xv.w;
        float4 w = *reinterpret_cast<const float4*>(Wo1 + (size_t)n * 64 + jj);
        wg[n][jj] = w.x; wg[n][jj + 1] = w.y; wg[n][jj + 2] = w.z; wg[n][jj + 3] = w.w;
    }
    if (tid < 128) wo2[tid] = Wo2[tid];
    __syncthreads();
    int j = tid & 63;
    int g = tid >> 6;
    float bj = bo1[j];
    for (int i = 0; i < 16; ++i) {
        int n = g * 16 + i;
        float a = bj;
#pragma unroll
        for (int k = 0; k < 64; ++k) a += xsg[n][k] * wg[k][j];
        hs[n][j] = leaky(a);
    }
    __syncthreads();
    if (tid < 128) {
        int n = tid >> 1;
        int j2 = tid & 1;
        float a = bo2[j2];
#pragma unroll
        for (int k = 0; k < 64; ++k) a += hs[n][k] * wo2[k * 2 + j2];
        if (n0 + n < N) out[(size_t)(n0 + n) * 2 + j2] = 1.f / (1.f + expf(-a));
    }
}

// ---------------------------------------------------------------------------
extern "C" void kernel_launch(void* const* d_in, const int* in_sizes, int n_in,
                              void* d_out, int out_size, void* d_ws, size_t ws_size,
                              hipStream_t stream) {
    const float* screen   = (const float*)d_in[0];
    const float* des      = (const float*)d_in[1];
    const float* tweet    = (const float*)d_in[2];
    const float* profile  = (const float*)d_in[3];
    const float* personal = (const float*)d_in[4];
    const int*   edge     = (const int*)d_in[5];
    const float* Ws  = (const float*)d_in[6],  *bs  = (const float*)d_in[7];
    const float* Wd  = (const float*)d_in[8],  *bd  = (const float*)d_in[9];
    const float* Wt  = (const float*)d_in[10], *bt  = (const float*)d_in[11];
    const float* Wp  = (const float*)d_in[12], *bp  = (const float*)d_in[13];
    const float* Wpe = (const float*)d_in[14], *bpe = (const float*)d_in[15];
    const float* Wl  = (const float*)d_in[16], *bl  = (const float*)d_in[17];
    const float* Wg1 = (const float*)d_in[18], *bg1 = (const float*)d_in[19];
    const float* Wg2 = (const float*)d_in[20], *bg2 = (const float*)d_in[21];
    const float* Wg3 = (const float*)d_in[22], *bg3 = (const float*)d_in[23];
    const float* Wo1 = (const float*)d_in[24], *bo1 = (const float*)d_in[25];
    const float* Wo2 = (const float*)d_in[26], *bo2 = (const float*)d_in[27];

    const int N = in_sizes[0] / 768;   // 50000
    const int E = in_sizes[5] / 2;     // 1600000
    const int* row = edge;
    const int* col = edge + E;

    size_t off = 0;
    auto alloc = [&](size_t bytes) -> void* {
        void* p = (char*)d_ws + off;
        off += (bytes + 255) & ~(size_t)255;
        return p;
    };
    const size_t NF = (size_t)N * 64;
    float* x1   = (float*)alloc(NF * 4);
    float* xa   = (float*)alloc(NF * 4);
    float* xb   = (float*)alloc(NF * 4);
    unsigned short* z = (unsigned short*)alloc(NF * 2);
    float* dinv = (float*)alloc((size_t)N * 4);
    int* deg  = (int*)alloc((size_t)N * 4);
    int* part = (int*)alloc((size_t)N * 4);
    int* offs = (int*)alloc((size_t)(N + 1) * 4);
    int* pos  = (int*)alloc((size_t)N * 4);
    int* csr  = (int*)alloc((size_t)E * 4);
    const int NB = (N + 255) / 256;
    int* bsum = (int*)alloc((size_t)NB * 4);
    int* boff = (int*)alloc((size_t)NB * 4);
    (void)ws_size; (void)n_in; (void)out_size;

    // CSR build
    hipMemsetAsync(deg, 0, (size_t)N * 4, stream);
    k_deg<<<(E + 255) / 256, 256, 0, stream>>>(col, E, deg);
    k_scan_part<<<NB, 256, 0, stream>>>(deg, part, bsum, N);
    k_scan_sums<<<1, 256, 0, stream>>>(bsum, boff, NB, offs + N);
    k_scan_final<<<NB, 256, 0, stream>>>(part, boff, deg, offs, pos, dinv, N);
    k_fill<<<(E + 255) / 256, 256, 0, stream>>>(row, col, E, pos, csr);

    // Phase A: MFMA feature linears + fused tiny linears
    const int NG = (N + 127) / 128;
    const int NSM = (N + 511) / 512;
    k_featB<<<NG * 3 + NSM, 512, 0, stream>>>(screen, des, tweet,
                                              Ws, bs, Wd, bd, Wt, bt,
                                              profile, personal, Wp, bp, Wpe, bpe,
                                              x1, N, NG);

    const int NGB = (N + 63) / 64;
    const int NAB = (N + 3) / 4;
    // layer 1 (lin + matmul fused)
    k_lin1<<<NGB, 256, 0, stream>>>(x1, Wl, bl, Wg1, dinv, z, N);
    k_agg<<<NAB, 256, 0, stream>>>(z, offs, csr, dinv, bg1, x1, xb, N);
    // layer 2
    k_mm64<<<NGB, 256, 0, stream>>>(xb, Wg2, dinv, z, N);
    k_agg<<<NAB, 256, 0, stream>>>(z, offs, csr, dinv, bg2, x1, xa, N);
    // layer 3
    k_mm64<<<NGB, 256, 0, stream>>>(xa, Wg3, dinv, z, N);
    k_agg<<<NAB, 256, 0, stream>>>(z, offs, csr, dinv, bg3, x1, xb, N);

    // head
    k_head<<<NGB, 256, 0, stream>>>(xb, Wo1, bo1, Wo2, bo2, (float*)d_out, N);
}